// Round 5
// baseline (820.861 us; speedup 1.0000x reference)
//
#include <hip/hip_runtime.h>

typedef unsigned short u16;
typedef unsigned int u32;
typedef __bf16 bf16x8 __attribute__((ext_vector_type(8)));
typedef float f32x4 __attribute__((ext_vector_type(4)));

__device__ __forceinline__ u16 f2bf(float f) {
    u32 u = __float_as_uint(f);
    u32 r = (u + 0x7fffu + ((u >> 16) & 1u)) >> 16;
    return (u16)r;
}
__device__ __forceinline__ float bf2f(u16 v) { return __uint_as_float(((u32)v) << 16); }
__device__ __forceinline__ u32 pack2(float lo, float hi) {
    return (u32)f2bf(lo) | (((u32)f2bf(hi)) << 16);
}

// ---------------- degree / dinv ----------------

__global__ void deg_kernel(const int* __restrict__ ei, int E, int* __restrict__ cnt) {
    int i = blockIdx.x * blockDim.x + threadIdx.x;
    if (i < E) atomicAdd(&cnt[ei[E + i]], 1);
}

__global__ void dinv_kernel(const int* __restrict__ cnt, float* __restrict__ dinv, int N) {
    int i = blockIdx.x * blockDim.x + threadIdx.x;
    if (i < N) dinv[i] = 1.0f / sqrtf((float)cnt[i] + 1.0f);
}

// ---------------- multi-block exclusive scan (3 passes) ----------------

__global__ __launch_bounds__(256) void scan1_k(const int* __restrict__ cnt,
                                               int* __restrict__ offs,
                                               int* __restrict__ bsum, int N) {
    __shared__ int lds[256];
    int t = threadIdx.x;
    int idx0 = blockIdx.x * 1024 + t * 4;
    int v[4], s = 0;
#pragma unroll
    for (int k = 0; k < 4; k++) {
        int i = idx0 + k;
        v[k] = (i < N) ? cnt[i] : 0;
        s += v[k];
    }
    lds[t] = s;
    __syncthreads();
    for (int off = 1; off < 256; off <<= 1) {
        int u = 0;
        if (t >= off) u = lds[t - off];
        __syncthreads();
        lds[t] += u;
        __syncthreads();
    }
    int run = lds[t] - s;
#pragma unroll
    for (int k = 0; k < 4; k++) {
        int i = idx0 + k;
        if (i < N) offs[i] = run;
        run += v[k];
    }
    if (t == 255) bsum[blockIdx.x] = lds[255];
}

__global__ __launch_bounds__(256) void scan2_k(int* __restrict__ bsum, int* __restrict__ boff,
                                               int nb, int* __restrict__ totp) {
    __shared__ int lds[256];
    int t = threadIdx.x;
    int s = (t < nb) ? bsum[t] : 0;
    lds[t] = s;
    __syncthreads();
    for (int off = 1; off < 256; off <<= 1) {
        int u = 0;
        if (t >= off) u = lds[t - off];
        __syncthreads();
        lds[t] += u;
        __syncthreads();
    }
    if (t < nb) boff[t] = lds[t] - s;
    if (t == 255) *totp = lds[255];
}

__global__ void scan3_k(int* __restrict__ offs, int* __restrict__ cursor,
                        const int* __restrict__ boff, int N) {
    int i = blockIdx.x * blockDim.x + threadIdx.x;
    if (i < N) {
        int v = offs[i] + boff[i >> 10];
        offs[i] = v;
        cursor[i] = v;
    }
}

__global__ void fill_kernel(const int* __restrict__ ei, int E,
                            const float* __restrict__ dinv, int* __restrict__ cursor,
                            int* __restrict__ csr_src, float* __restrict__ csr_w) {
    int i = blockIdx.x * blockDim.x + threadIdx.x;
    if (i < E) {
        int r = ei[i];
        int c = ei[E + i];
        int pos = atomicAdd(&cursor[c], 1);
        csr_src[pos] = r;
        csr_w[pos] = dinv[r];
    }
}

// ---------------- float -> bf16 conversion (packed pairs) ----------------

__global__ void cvt_f2bf_k(const float* __restrict__ src, u16* __restrict__ dst, int npairs) {
    u32* d = (u32*)dst;
    for (int i = blockIdx.x * blockDim.x + threadIdx.x; i < npairs;
         i += blockDim.x * gridDim.x) {
        float lo = src[2 * i], hi = src[2 * i + 1];
        d[i] = pack2(lo, hi);
    }
}

// ---------------- weight packing into MFMA-fragment layout ----------------
// B fragment for mfma_f32_16x16x32_bf16: lane l holds B[k=(l>>4)*8+j][n=l&15], j=0..7
// packed layout: [ks][jt][lane][8], stride 512 elements per (ks,jt)

struct PackArgs {
    const float* W[9];
    const float* B[9];
    int Kin[9], Nout[9], KS[9], NT[9], wOff[9], bOff[9];
};

__global__ void pack_weights(PackArgs pa, u16* __restrict__ wpack, float* __restrict__ bpack) {
    int L = blockIdx.y;
    int KS = pa.KS[L], NT = pa.NT[L], Kin = pa.Kin[L], Nout = pa.Nout[L];
    int wtot = KS * NT * 512;
    int btot = NT * 16;
    const float* W = pa.W[L];
    const float* Bb = pa.B[L];
    u16* wp = wpack + pa.wOff[L];
    float* bp = bpack + pa.bOff[L];
    for (int idx = blockIdx.x * blockDim.x + threadIdx.x; idx < wtot + btot;
         idx += blockDim.x * gridDim.x) {
        if (idx < wtot) {
            int j = idx & 7;
            int lane = (idx >> 3) & 63;
            int pos = idx >> 9;
            int jt = pos % NT;
            int ks = pos / NT;
            int k = ks * 32 + ((lane >> 4) & 3) * 8 + j;
            int n = jt * 16 + (lane & 15);
            u16 v = 0;
            if (k < Kin && n < Nout) v = f2bf(W[k * Nout + n]);
            wp[idx] = v;
        } else {
            int n = idx - wtot;
            float v = 0.f;
            if (n < Nout) v = Bb[n];
            bp[n] = v;
        }
    }
}

// ---------------- fused propagate+GEMM ----------------
// Lane l of a wave gathers the propagated slice of row m0+(l&15), channels
// (l>>4)*8..+8 within the current ks 32-block — which IS the MFMA A-fragment
// layout. ks-outer keeps gather accumulators at 8 fp32.

template <int Cp>
__device__ __forceinline__ bf16x8 gather_slice(const u16* __restrict__ h, int sliceOff,
                                               float dn, int row, int beg, int end,
                                               const int* __restrict__ csr_src,
                                               const float* __restrict__ csr_w) {
    float a[8];
    {
        bf16x8 sv = *(const bf16x8*)(h + (size_t)row * Cp + sliceOff);
#pragma unroll
        for (int j = 0; j < 8; j++) a[j] = dn * (float)sv[j];
    }
    int e = beg;
    for (; e + 1 < end; e += 2) {
        int s0 = csr_src[e], s1 = csr_src[e + 1];
        float w0 = csr_w[e], w1 = csr_w[e + 1];
        bf16x8 v0 = *(const bf16x8*)(h + (size_t)s0 * Cp + sliceOff);
        bf16x8 v1 = *(const bf16x8*)(h + (size_t)s1 * Cp + sliceOff);
#pragma unroll
        for (int j = 0; j < 8; j++) {
            a[j] = fmaf(w0, (float)v0[j], a[j]);
            a[j] = fmaf(w1, (float)v1[j], a[j]);
        }
    }
    if (e < end) {
        int s0 = csr_src[e];
        float w0 = csr_w[e];
        bf16x8 v0 = *(const bf16x8*)(h + (size_t)s0 * Cp + sliceOff);
#pragma unroll
        for (int j = 0; j < 8; j++) a[j] = fmaf(w0, (float)v0[j], a[j]);
    }
    bf16x8 r;
#pragma unroll
    for (int j = 0; j < 8; j++) r[j] = (__bf16)(dn * a[j]);
    return r;
}

// single-output: OP 1=relu, 2=sigmoid; OUTF 0=bf16, 1=f32
template <int KS, int NT, int OP, int OUTF>
__global__ __launch_bounds__(256) void fused_pg_k(const u16* __restrict__ h,
                                                  const u16* __restrict__ Bp,
                                                  const float* __restrict__ bias,
                                                  void* __restrict__ Cv, int ldc,
                                                  const float* __restrict__ dinv,
                                                  const int* __restrict__ offs,
                                                  const int* __restrict__ csr_src,
                                                  const float* __restrict__ csr_w, int M) {
    constexpr int Cp = KS * 32;
    const int lane = threadIdx.x & 63;
    const int wave = threadIdx.x >> 6;
    int m0 = (blockIdx.x * 4 + wave) * 16;
    if (m0 >= M) return;
    int row = m0 + (lane & 15);
    if (row >= M) row = M - 1;
    const int q = lane >> 4;
    float dn = dinv[row];
    int beg = offs[row], end = offs[row + 1];
    f32x4 acc[NT];
#pragma unroll
    for (int j = 0; j < NT; j++) acc[j] = (f32x4){0.f, 0.f, 0.f, 0.f};
#pragma unroll
    for (int ks = 0; ks < KS; ks++) {
        bf16x8 af = gather_slice<Cp>(h, ks * 32 + q * 8, dn, row, beg, end, csr_src, csr_w);
#pragma unroll
        for (int j = 0; j < NT; j++) {
            bf16x8 bf = *(const bf16x8*)(Bp + lane * 8 + (ks * NT + j) * 512);
            acc[j] = __builtin_amdgcn_mfma_f32_16x16x32_bf16(af, bf, acc[j], 0, 0, 0);
        }
    }
    int mrow = m0 + q * 4;
#pragma unroll
    for (int j = 0; j < NT; j++) {
        int n = j * 16 + (lane & 15);
        float b = bias[n];
#pragma unroll
        for (int r = 0; r < 4; r++) {
            int m = mrow + r;
            if (m < M) {
                float v = acc[j][r] + b;
                if (OP == 1) v = fmaxf(v, 0.f);
                if (OP == 2) v = 1.f / (1.f + expf(-v));
                if (OUTF) ((float*)Cv)[(size_t)m * ldc + n] = v;
                else ((u16*)Cv)[(size_t)m * ldc + n] = f2bf(v);
            }
        }
    }
}

// dual-output relu (shared gather), bf16 out
template <int KS, int NT1, int NT2>
__global__ __launch_bounds__(256) void fused_pg_dual_k(const u16* __restrict__ h,
                                                       const u16* __restrict__ Bp1,
                                                       const float* __restrict__ bias1,
                                                       u16* __restrict__ C1o, int ld1,
                                                       const u16* __restrict__ Bp2,
                                                       const float* __restrict__ bias2,
                                                       u16* __restrict__ C2o, int ld2,
                                                       const float* __restrict__ dinv,
                                                       const int* __restrict__ offs,
                                                       const int* __restrict__ csr_src,
                                                       const float* __restrict__ csr_w, int M) {
    constexpr int Cp = KS * 32;
    const int lane = threadIdx.x & 63;
    const int wave = threadIdx.x >> 6;
    int m0 = (blockIdx.x * 4 + wave) * 16;
    if (m0 >= M) return;
    int row = m0 + (lane & 15);
    if (row >= M) row = M - 1;
    const int q = lane >> 4;
    float dn = dinv[row];
    int beg = offs[row], end = offs[row + 1];
    f32x4 acc1[NT1], acc2[NT2];
#pragma unroll
    for (int j = 0; j < NT1; j++) acc1[j] = (f32x4){0.f, 0.f, 0.f, 0.f};
#pragma unroll
    for (int j = 0; j < NT2; j++) acc2[j] = (f32x4){0.f, 0.f, 0.f, 0.f};
#pragma unroll
    for (int ks = 0; ks < KS; ks++) {
        bf16x8 af = gather_slice<Cp>(h, ks * 32 + q * 8, dn, row, beg, end, csr_src, csr_w);
#pragma unroll
        for (int j = 0; j < NT1; j++) {
            bf16x8 bf = *(const bf16x8*)(Bp1 + lane * 8 + (ks * NT1 + j) * 512);
            acc1[j] = __builtin_amdgcn_mfma_f32_16x16x32_bf16(af, bf, acc1[j], 0, 0, 0);
        }
#pragma unroll
        for (int j = 0; j < NT2; j++) {
            bf16x8 bf = *(const bf16x8*)(Bp2 + lane * 8 + (ks * NT2 + j) * 512);
            acc2[j] = __builtin_amdgcn_mfma_f32_16x16x32_bf16(af, bf, acc2[j], 0, 0, 0);
        }
    }
    int mrow = m0 + q * 4;
#pragma unroll
    for (int j = 0; j < NT1; j++) {
        int n = j * 16 + (lane & 15);
        float b = bias1[n];
#pragma unroll
        for (int r = 0; r < 4; r++) {
            int m = mrow + r;
            if (m < M) C1o[(size_t)m * ld1 + n] = f2bf(fmaxf(acc1[j][r] + b, 0.f));
        }
    }
#pragma unroll
    for (int j = 0; j < NT2; j++) {
        int n = j * 16 + (lane & 15);
        float b = bias2[n];
#pragma unroll
        for (int r = 0; r < 4; r++) {
            int m = mrow + r;
            if (m < M) C2o[(size_t)m * ld2 + n] = f2bf(fmaxf(acc2[j][r] + b, 0.f));
        }
    }
}

// dual mu/ls GEMM + reparametrize epilogue, bf16 out, zero-padded cols >= CLIM
template <int KS, int NT, int CLIM>
__global__ __launch_bounds__(256) void fused_pg_reparam_k(const u16* __restrict__ h,
                                                          const u16* __restrict__ BpM,
                                                          const float* __restrict__ biasM,
                                                          const u16* __restrict__ BpL,
                                                          const float* __restrict__ biasL,
                                                          const u16* __restrict__ epsb,
                                                          u16* __restrict__ out, int ldc,
                                                          const float* __restrict__ dinv,
                                                          const int* __restrict__ offs,
                                                          const int* __restrict__ csr_src,
                                                          const float* __restrict__ csr_w,
                                                          int M) {
    constexpr int Cp = KS * 32;
    const int lane = threadIdx.x & 63;
    const int wave = threadIdx.x >> 6;
    int m0 = (blockIdx.x * 4 + wave) * 16;
    if (m0 >= M) return;
    int row = m0 + (lane & 15);
    if (row >= M) row = M - 1;
    const int q = lane >> 4;
    float dn = dinv[row];
    int beg = offs[row], end = offs[row + 1];
    f32x4 accM[NT], accL[NT];
#pragma unroll
    for (int j = 0; j < NT; j++) {
        accM[j] = (f32x4){0.f, 0.f, 0.f, 0.f};
        accL[j] = (f32x4){0.f, 0.f, 0.f, 0.f};
    }
#pragma unroll
    for (int ks = 0; ks < KS; ks++) {
        bf16x8 af = gather_slice<Cp>(h, ks * 32 + q * 8, dn, row, beg, end, csr_src, csr_w);
#pragma unroll
        for (int j = 0; j < NT; j++) {
            bf16x8 bm = *(const bf16x8*)(BpM + lane * 8 + (ks * NT + j) * 512);
            accM[j] = __builtin_amdgcn_mfma_f32_16x16x32_bf16(af, bm, accM[j], 0, 0, 0);
            bf16x8 bl = *(const bf16x8*)(BpL + lane * 8 + (ks * NT + j) * 512);
            accL[j] = __builtin_amdgcn_mfma_f32_16x16x32_bf16(af, bl, accL[j], 0, 0, 0);
        }
    }
    int mrow = m0 + q * 4;
#pragma unroll
    for (int j = 0; j < NT; j++) {
        int n = j * 16 + (lane & 15);
        float bm = biasM[n];
        float bl = biasL[n];
#pragma unroll
        for (int r = 0; r < 4; r++) {
            int m = mrow + r;
            if (m < M) {
                float v = 0.f;
                if (n < CLIM) {
                    float e = bf2f(epsb[(size_t)m * CLIM + n]);
                    v = (accM[j][r] + bm) + e * expf(accL[j][r] + bl) * 0.1f;
                }
                out[(size_t)m * ldc + n] = f2bf(v);
            }
        }
    }
}

// ---------------- host launch ----------------

extern "C" void kernel_launch(void* const* d_in, const int* in_sizes, int n_in,
                              void* d_out, int out_size, void* d_ws, size_t ws_size,
                              hipStream_t stream) {
    const float* x = (const float*)d_in[0];
    const int* ei = (const int*)d_in[1];
    const float* eps_e = (const float*)d_in[2];
    const float* eps_n = (const float*)d_in[3];
    int N = in_sizes[0] / 96;
    int E = in_sizes[1] / 2;

    char* p = (char*)d_ws;
    auto alloc = [&](size_t bytes) -> char* {
        char* r = p;
        p += (bytes + 255) & ~(size_t)255;
        return r;
    };
    int* cnt = (int*)alloc((size_t)N * 4);
    float* dinv = (float*)alloc((size_t)N * 4);
    int* offs = (int*)alloc((size_t)(N + 1) * 4);
    int* cursor = (int*)alloc((size_t)N * 4);
    int* bsum = (int*)alloc(256 * 4);
    int* boff = (int*)alloc(256 * 4);
    int* csr_src = (int*)alloc((size_t)E * 4);
    float* csr_w = (float*)alloc((size_t)E * 4);
    u16* wpack = (u16*)alloc(167936 * 2);
    float* bpack = (float*)alloc(1248 * 4);
    size_t bufBytes = (size_t)N * 192 * 2;
    u16* bufA = (u16*)alloc(bufBytes);
    u16* bufB = (u16*)alloc(bufBytes);
    u16* bufC = (u16*)alloc(bufBytes);
    u16* bufD = (u16*)alloc(bufBytes);
    u16* epsEb = (u16*)alloc((size_t)N * 163 * 2);
    u16* epsNb = (u16*)alloc((size_t)N * 96 * 2);

    // conversions first (overlap with setup; bf16 halves later read bytes)
    cvt_f2bf_k<<<2048, 256, 0, stream>>>(eps_e, epsEb, N * 163 / 2);
    cvt_f2bf_k<<<2048, 256, 0, stream>>>(eps_n, epsNb, N * 48);
    cvt_f2bf_k<<<2048, 256, 0, stream>>>(x, bufD, N * 48);  // xb -> D

    hipMemsetAsync(cnt, 0, (size_t)N * 4, stream);
    int gE = (E + 255) / 256, gN = (N + 255) / 256;
    deg_kernel<<<gE, 256, 0, stream>>>(ei, E, cnt);
    dinv_kernel<<<gN, 256, 0, stream>>>(cnt, dinv, N);
    int nb = (N + 1023) / 1024;
    scan1_k<<<nb, 256, 0, stream>>>(cnt, offs, bsum, N);
    scan2_k<<<1, 256, 0, stream>>>(bsum, boff, nb, offs + N);
    scan3_k<<<gN, 256, 0, stream>>>(offs, cursor, boff, N);
    fill_kernel<<<gE, 256, 0, stream>>>(ei, E, dinv, cursor, csr_src, csr_w);

    // layers: {w1e,w2e,wme,wle,w4e,w1n,wmn,wln,w5n}
    static const int wi[9] = {4, 6, 8, 10, 12, 14, 16, 18, 20};
    static const int bi[9] = {5, 7, 9, 11, 13, 15, 17, 19, 21};
    static const int Kin[9] = {96, 125, 144, 144, 163, 96, 96, 96, 96};
    static const int Nout[9] = {125, 144, 163, 163, 192, 96, 96, 96, 96};
    static const int KSa[9] = {3, 4, 5, 5, 6, 3, 3, 3, 3};
    static const int NTa[9] = {8, 10, 12, 12, 12, 6, 6, 6, 6};
    static const int wOff[9] = {0, 12288, 32768, 63488, 94208, 131072, 140288, 149504, 158720};
    static const int bOff[9] = {0, 128, 288, 480, 672, 864, 960, 1056, 1152};
    PackArgs pa;
    for (int i = 0; i < 9; i++) {
        pa.W[i] = (const float*)d_in[wi[i]];
        pa.B[i] = (const float*)d_in[bi[i]];
        pa.Kin[i] = Kin[i]; pa.Nout[i] = Nout[i];
        pa.KS[i] = KSa[i];  pa.NT[i] = NTa[i];
        pa.wOff[i] = wOff[i]; pa.bOff[i] = bOff[i];
    }
    pack_weights<<<dim3(32, 9), 256, 0, stream>>>(pa, wpack, bpack);

    const int gg = (N + 63) / 64;  // 64 rows/block (4 waves x 16 rows)

    // e1 = relu(P(xb) W1e+b1e) -> C (128); n1 = relu(P(xb) W1n+b1n) -> B (96)
    fused_pg_dual_k<3, 8, 6><<<gg, 256, 0, stream>>>(
        bufD, wpack + 0, bpack + 0, bufC, 128, wpack + 131072, bpack + 864, bufB, 96,
        dinv, offs, csr_src, csr_w, N);
    // e2 = relu(P(e1) W2e + b2e) -> A (160, cols 144.. auto-zero)
    fused_pg_k<4, 10, 1, 0><<<gg, 256, 0, stream>>>(
        bufC, wpack + 12288, bpack + 128, bufA, 160, dinv, offs, csr_src, csr_w, N);
    // lat = (P(e2) Wme+bme) + eps_e*exp(P(e2) Wle+ble)/10 -> C (192, cols 163.. zero)
    fused_pg_reparam_k<5, 12, 163><<<gg, 256, 0, stream>>>(
        bufA, wpack + 32768, bpack + 288, wpack + 63488, bpack + 480, epsEb, bufC, 192,
        dinv, offs, csr_src, csr_w, N);
    // edges = sigmoid(P(lat) W4e + b4e) -> d_out[0 : 192N] (f32)
    fused_pg_k<6, 12, 2, 1><<<gg, 256, 0, stream>>>(
        bufC, wpack + 94208, bpack + 672, (float*)d_out, 192, dinv, offs, csr_src, csr_w, N);
    // nn = (P(n1) Wmn+bmn) + eps_n*exp(P(n1) Wln+bln)/10 -> D (96)
    fused_pg_reparam_k<3, 6, 96><<<gg, 256, 0, stream>>>(
        bufB, wpack + 140288, bpack + 960, wpack + 149504, bpack + 1056, epsNb, bufD, 96,
        dinv, offs, csr_src, csr_w, N);
    // nodes = relu(P(nn) W5n + b5n) -> d_out[192N : 288N] (f32)
    fused_pg_k<3, 6, 1, 1><<<gg, 256, 0, stream>>>(
        bufD, wpack + 158720, bpack + 1152, (float*)d_out + (size_t)N * 192, 96,
        dinv, offs, csr_src, csr_w, N);
}

// Round 6
// 671.463 us; speedup vs baseline: 1.2225x; 1.2225x over previous
//
#include <hip/hip_runtime.h>

typedef unsigned short u16;
typedef unsigned int u32;
typedef __bf16 bf16x8 __attribute__((ext_vector_type(8)));
typedef float f32x4 __attribute__((ext_vector_type(4)));

__device__ __forceinline__ u16 f2bf(float f) {
    u32 u = __float_as_uint(f);
    u32 r = (u + 0x7fffu + ((u >> 16) & 1u)) >> 16;
    return (u16)r;
}
__device__ __forceinline__ float bf2f(u16 v) { return __uint_as_float(((u32)v) << 16); }
__device__ __forceinline__ float bf_lo(u32 v) { return __uint_as_float(v << 16); }
__device__ __forceinline__ float bf_hi(u32 v) { return __uint_as_float(v & 0xffff0000u); }
__device__ __forceinline__ u32 pack2(float lo, float hi) {
    return (u32)f2bf(lo) | (((u32)f2bf(hi)) << 16);
}

// ---------------- degree / dinv ----------------

__global__ void deg_kernel(const int* __restrict__ ei, int E, int* __restrict__ cnt) {
    int i = blockIdx.x * blockDim.x + threadIdx.x;
    if (i < E) atomicAdd(&cnt[ei[E + i]], 1);
}

__global__ void dinv_kernel(const int* __restrict__ cnt, float* __restrict__ dinv, int N) {
    int i = blockIdx.x * blockDim.x + threadIdx.x;
    if (i < N) dinv[i] = 1.0f / sqrtf((float)cnt[i] + 1.0f);
}

// ---------------- multi-block exclusive scan (3 passes) ----------------

__global__ __launch_bounds__(256) void scan1_k(const int* __restrict__ cnt,
                                               int* __restrict__ offs,
                                               int* __restrict__ bsum, int N) {
    __shared__ int lds[256];
    int t = threadIdx.x;
    int idx0 = blockIdx.x * 1024 + t * 4;
    int v[4], s = 0;
#pragma unroll
    for (int k = 0; k < 4; k++) {
        int i = idx0 + k;
        v[k] = (i < N) ? cnt[i] : 0;
        s += v[k];
    }
    lds[t] = s;
    __syncthreads();
    for (int off = 1; off < 256; off <<= 1) {
        int u = 0;
        if (t >= off) u = lds[t - off];
        __syncthreads();
        lds[t] += u;
        __syncthreads();
    }
    int run = lds[t] - s;
#pragma unroll
    for (int k = 0; k < 4; k++) {
        int i = idx0 + k;
        if (i < N) offs[i] = run;
        run += v[k];
    }
    if (t == 255) bsum[blockIdx.x] = lds[255];
}

__global__ __launch_bounds__(256) void scan2_k(int* __restrict__ bsum, int* __restrict__ boff,
                                               int nb, int* __restrict__ totp) {
    __shared__ int lds[256];
    int t = threadIdx.x;
    int s = (t < nb) ? bsum[t] : 0;
    lds[t] = s;
    __syncthreads();
    for (int off = 1; off < 256; off <<= 1) {
        int u = 0;
        if (t >= off) u = lds[t - off];
        __syncthreads();
        lds[t] += u;
        __syncthreads();
    }
    if (t < nb) boff[t] = lds[t] - s;
    if (t == 255) *totp = lds[255];
}

__global__ void scan3_k(int* __restrict__ offs, int* __restrict__ cursor,
                        const int* __restrict__ boff, int N) {
    int i = blockIdx.x * blockDim.x + threadIdx.x;
    if (i < N) {
        int v = offs[i] + boff[i >> 10];
        offs[i] = v;
        cursor[i] = v;
    }
}

// csr entry packed as int2 {src, w-as-bits}: one 8B load per edge in the hot loop
__global__ void fill_kernel(const int* __restrict__ ei, int E,
                            const float* __restrict__ dinv, int* __restrict__ cursor,
                            int2* __restrict__ csr) {
    int i = blockIdx.x * blockDim.x + threadIdx.x;
    if (i < E) {
        int r = ei[i];
        int c = ei[E + i];
        int pos = atomicAdd(&cursor[c], 1);
        csr[pos] = make_int2(r, __float_as_int(dinv[r]));
    }
}

// ---------------- float -> bf16 conversion (packed pairs) ----------------

__global__ void cvt_f2bf_k(const float* __restrict__ src, u16* __restrict__ dst, int npairs) {
    u32* d = (u32*)dst;
    for (int i = blockIdx.x * blockDim.x + threadIdx.x; i < npairs;
         i += blockDim.x * gridDim.x) {
        float lo = src[2 * i], hi = src[2 * i + 1];
        d[i] = pack2(lo, hi);
    }
}

// ---------------- weight packing into MFMA-fragment layout ----------------
// B fragment for mfma_f32_16x16x32_bf16: lane l holds B[k=(l>>4)*8+j][n=l&15], j=0..7
// packed layout: [ks][jt][lane][8], stride 512 elements per (ks,jt)

struct PackArgs {
    const float* W[9];
    const float* B[9];
    int Kin[9], Nout[9], KS[9], NT[9], wOff[9], bOff[9];
};

__global__ void pack_weights(PackArgs pa, u16* __restrict__ wpack, float* __restrict__ bpack) {
    int L = blockIdx.y;
    int KS = pa.KS[L], NT = pa.NT[L], Kin = pa.Kin[L], Nout = pa.Nout[L];
    int wtot = KS * NT * 512;
    int btot = NT * 16;
    const float* W = pa.W[L];
    const float* Bb = pa.B[L];
    u16* wp = wpack + pa.wOff[L];
    float* bp = bpack + pa.bOff[L];
    for (int idx = blockIdx.x * blockDim.x + threadIdx.x; idx < wtot + btot;
         idx += blockDim.x * gridDim.x) {
        if (idx < wtot) {
            int j = idx & 7;
            int lane = (idx >> 3) & 63;
            int pos = idx >> 9;
            int jt = pos % NT;
            int ks = pos / NT;
            int k = ks * 32 + ((lane >> 4) & 3) * 8 + j;
            int n = jt * 16 + (lane & 15);
            u16 v = 0;
            if (k < Kin && n < Nout) v = f2bf(W[k * Nout + n]);
            wp[idx] = v;
        } else {
            int n = idx - wtot;
            float v = 0.f;
            if (n < Nout) v = Bb[n];
            bp[n] = v;
        }
    }
}

// ---------------- propagation: out[n] = dinv[n]*(sum_e dinv[src]*h[src] + dinv[n]*h[n]) ----
// one wave per node; lanes cover channel pairs (bf16x2 = 4B chunks); 4-way edge unroll

template <int C2>
__global__ __launch_bounds__(256) void propagate_k(const u16* __restrict__ h,
                                                   u16* __restrict__ out,
                                                   const float* __restrict__ dinv,
                                                   const int* __restrict__ offs,
                                                   const int2* __restrict__ csr, int N) {
    constexpr int Cp = C2 * 2;
    const int lane = threadIdx.x & 63;
    int wid = (blockIdx.x * blockDim.x + threadIdx.x) >> 6;
    int nw = (gridDim.x * blockDim.x) >> 6;
    constexpr bool HAS1 = (C2 > 64);
    const bool a0 = lane < (C2 < 64 ? C2 : 64);
    const bool a1 = HAS1 && (lane < C2 - 64);
    const int c0 = lane, c1 = lane + 64;
    for (int n = wid; n < N; n += nw) {
        float dn = dinv[n];
        int beg = offs[n], end = offs[n + 1];
        float x0 = 0.f, y0 = 0.f, x1 = 0.f, y1 = 0.f;
        {
            const u32* hp = (const u32*)(h + (size_t)n * Cp);
            if (a0) { u32 v = hp[c0]; x0 = dn * bf_lo(v); y0 = dn * bf_hi(v); }
            if (a1) { u32 v = hp[c1]; x1 = dn * bf_lo(v); y1 = dn * bf_hi(v); }
        }
        int e = beg;
        for (; e + 3 < end; e += 4) {  // 4-way unroll: 4 outstanding row-gathers
            int2 c_0 = csr[e], c_1 = csr[e + 1], c_2 = csr[e + 2], c_3 = csr[e + 3];
            float w0 = __int_as_float(c_0.y), w1 = __int_as_float(c_1.y);
            float w2 = __int_as_float(c_2.y), w3 = __int_as_float(c_3.y);
            const u32* p0 = (const u32*)(h + (size_t)c_0.x * Cp);
            const u32* p1 = (const u32*)(h + (size_t)c_1.x * Cp);
            const u32* p2 = (const u32*)(h + (size_t)c_2.x * Cp);
            const u32* p3 = (const u32*)(h + (size_t)c_3.x * Cp);
            if (a0) {
                u32 u0 = p0[c0], u1 = p1[c0], u2 = p2[c0], u3 = p3[c0];
                x0 = fmaf(w0, bf_lo(u0), x0); y0 = fmaf(w0, bf_hi(u0), y0);
                x0 = fmaf(w1, bf_lo(u1), x0); y0 = fmaf(w1, bf_hi(u1), y0);
                x0 = fmaf(w2, bf_lo(u2), x0); y0 = fmaf(w2, bf_hi(u2), y0);
                x0 = fmaf(w3, bf_lo(u3), x0); y0 = fmaf(w3, bf_hi(u3), y0);
            }
            if (a1) {
                u32 u0 = p0[c1], u1 = p1[c1], u2 = p2[c1], u3 = p3[c1];
                x1 = fmaf(w0, bf_lo(u0), x1); y1 = fmaf(w0, bf_hi(u0), y1);
                x1 = fmaf(w1, bf_lo(u1), x1); y1 = fmaf(w1, bf_hi(u1), y1);
                x1 = fmaf(w2, bf_lo(u2), x1); y1 = fmaf(w2, bf_hi(u2), y1);
                x1 = fmaf(w3, bf_lo(u3), x1); y1 = fmaf(w3, bf_hi(u3), y1);
            }
        }
        for (; e < end; e++) {
            int2 ce = csr[e];
            float w0 = __int_as_float(ce.y);
            const u32* p0 = (const u32*)(h + (size_t)ce.x * Cp);
            if (a0) { u32 u = p0[c0]; x0 = fmaf(w0, bf_lo(u), x0); y0 = fmaf(w0, bf_hi(u), y0); }
            if (a1) { u32 u = p0[c1]; x1 = fmaf(w0, bf_lo(u), x1); y1 = fmaf(w0, bf_hi(u), y1); }
        }
        u32* op = (u32*)(out + (size_t)n * Cp);
        if (a0) op[c0] = pack2(dn * x0, dn * y0);
        if (a1) op[c1] = pack2(dn * x1, dn * y1);
    }
}

// ---------------- GEMM core (j-split over blockIdx.y) -------------
// A fragment: lane l holds A[m0 + (l&15)][ks*32 + (l>>4)*8 + j]
// C/D: col = lane&15, row = (lane>>4)*4 + reg

template <int KS, int NTtot, int NTH>
__device__ __forceinline__ void gemm_body(const u16* A, const u16* Bp, int jBase,
                                          f32x4* acc, int m0, int M, int lane) {
    constexpr int Kp = KS * 32;
    int row = m0 + (lane & 15);
    if (row >= M) row = M - 1;
    const u16* aptr = A + (size_t)row * Kp + ((lane >> 4) * 8);
    const u16* bptr = Bp + lane * 8;
#pragma unroll
    for (int j = 0; j < NTH; j++) acc[j] = (f32x4){0.f, 0.f, 0.f, 0.f};
#pragma unroll
    for (int ks = 0; ks < KS; ks++) {
        bf16x8 af = *(const bf16x8*)(aptr + ks * 32);
#pragma unroll
        for (int j = 0; j < NTH; j++) {
            bf16x8 bf = *(const bf16x8*)(bptr + (ks * NTtot + jBase + j) * 512);
            acc[j] = __builtin_amdgcn_mfma_f32_16x16x32_bf16(af, bf, acc[j], 0, 0, 0);
        }
    }
}

template <int KS, int NTtot, int NTH, int OP, int OUTF>
__global__ __launch_bounds__(256) void gemm_k(const u16* __restrict__ A,
                                              const u16* __restrict__ Bp,
                                              const float* __restrict__ bias,
                                              void* __restrict__ Cv, int M, int ldc) {
    const int lane = threadIdx.x & 63;
    const int wave = threadIdx.x >> 6;
    const int jBase = blockIdx.y * NTH;
    int m0 = (blockIdx.x * 4 + wave) * 16;
    if (m0 >= M) return;
    f32x4 acc[NTH];
    gemm_body<KS, NTtot, NTH>(A, Bp, jBase, acc, m0, M, lane);
    int mrow = m0 + (lane >> 4) * 4;
#pragma unroll
    for (int j = 0; j < NTH; j++) {
        int n = (jBase + j) * 16 + (lane & 15);
        float b = bias[n];
#pragma unroll
        for (int r = 0; r < 4; r++) {
            int m = mrow + r;
            if (m < M) {
                float v = acc[j][r] + b;
                if (OP == 1) v = fmaxf(v, 0.f);
                if (OP == 2) v = 1.f / (1.f + expf(-v));
                if (OUTF) ((float*)Cv)[(size_t)m * ldc + n] = v;
                else ((u16*)Cv)[(size_t)m * ldc + n] = f2bf(v);
            }
        }
    }
}

template <int KS, int NT1, int NT2>
__global__ __launch_bounds__(256) void gemm_dual_relu_k(const u16* __restrict__ A,
                                                        const u16* __restrict__ Bp1,
                                                        const float* __restrict__ bias1,
                                                        u16* __restrict__ C1o, int ld1,
                                                        const u16* __restrict__ Bp2,
                                                        const float* __restrict__ bias2,
                                                        u16* __restrict__ C2o, int ld2, int M) {
    const int lane = threadIdx.x & 63;
    const int wave = threadIdx.x >> 6;
    int m0 = (blockIdx.x * 4 + wave) * 16;
    if (m0 >= M) return;
    int mrow = m0 + (lane >> 4) * 4;
    if (blockIdx.y == 0) {
        f32x4 acc[NT1];
        gemm_body<KS, NT1, NT1>(A, Bp1, 0, acc, m0, M, lane);
#pragma unroll
        for (int j = 0; j < NT1; j++) {
            int n = j * 16 + (lane & 15);
            float b = bias1[n];
#pragma unroll
            for (int r = 0; r < 4; r++) {
                int m = mrow + r;
                if (m < M) C1o[(size_t)m * ld1 + n] = f2bf(fmaxf(acc[j][r] + b, 0.f));
            }
        }
    } else {
        f32x4 acc[NT2];
        gemm_body<KS, NT2, NT2>(A, Bp2, 0, acc, m0, M, lane);
#pragma unroll
        for (int j = 0; j < NT2; j++) {
            int n = j * 16 + (lane & 15);
            float b = bias2[n];
#pragma unroll
            for (int r = 0; r < 4; r++) {
                int m = mrow + r;
                if (m < M) C2o[(size_t)m * ld2 + n] = f2bf(fmaxf(acc[j][r] + b, 0.f));
            }
        }
    }
}

template <int KS, int NTtot, int NTH, int CLIM>
__global__ __launch_bounds__(256) void gemm_reparam_k(const u16* __restrict__ A,
                                                      const u16* __restrict__ BpM,
                                                      const float* __restrict__ biasM,
                                                      const u16* __restrict__ BpL,
                                                      const float* __restrict__ biasL,
                                                      const u16* __restrict__ epsb,
                                                      u16* __restrict__ out, int ldc, int M) {
    const int lane = threadIdx.x & 63;
    const int wave = threadIdx.x >> 6;
    const int jBase = blockIdx.y * NTH;
    int m0 = (blockIdx.x * 4 + wave) * 16;
    if (m0 >= M) return;
    int mrow = m0 + (lane >> 4) * 4;
    float epsv[NTH * 4];
#pragma unroll
    for (int j = 0; j < NTH; j++) {
        int n = (jBase + j) * 16 + (lane & 15);
#pragma unroll
        for (int r = 0; r < 4; r++) {
            int m = mrow + r;
            if (m >= M) m = M - 1;
            epsv[j * 4 + r] = (n < CLIM) ? bf2f(epsb[(size_t)m * CLIM + n]) : 0.f;
        }
    }
    constexpr int Kp = KS * 32;
    int row = m0 + (lane & 15);
    if (row >= M) row = M - 1;
    const u16* aptr = A + (size_t)row * Kp + ((lane >> 4) * 8);
    f32x4 accM[NTH], accL[NTH];
#pragma unroll
    for (int j = 0; j < NTH; j++) {
        accM[j] = (f32x4){0.f, 0.f, 0.f, 0.f};
        accL[j] = (f32x4){0.f, 0.f, 0.f, 0.f};
    }
#pragma unroll
    for (int ks = 0; ks < KS; ks++) {
        bf16x8 af = *(const bf16x8*)(aptr + ks * 32);
#pragma unroll
        for (int j = 0; j < NTH; j++) {
            bf16x8 bm = *(const bf16x8*)(BpM + lane * 8 + (ks * NTtot + jBase + j) * 512);
            accM[j] = __builtin_amdgcn_mfma_f32_16x16x32_bf16(af, bm, accM[j], 0, 0, 0);
            bf16x8 bl = *(const bf16x8*)(BpL + lane * 8 + (ks * NTtot + jBase + j) * 512);
            accL[j] = __builtin_amdgcn_mfma_f32_16x16x32_bf16(af, bl, accL[j], 0, 0, 0);
        }
    }
#pragma unroll
    for (int j = 0; j < NTH; j++) {
        int n = (jBase + j) * 16 + (lane & 15);
        float bm = biasM[n];
        float bl = biasL[n];
#pragma unroll
        for (int r = 0; r < 4; r++) {
            int m = mrow + r;
            if (m < M) {
                float v = 0.f;
                if (n < CLIM)
                    v = (accM[j][r] + bm) + epsv[j * 4 + r] * expf(accL[j][r] + bl) * 0.1f;
                out[(size_t)m * ldc + n] = f2bf(v);
            }
        }
    }
}

// ---------------- host launch ----------------

extern "C" void kernel_launch(void* const* d_in, const int* in_sizes, int n_in,
                              void* d_out, int out_size, void* d_ws, size_t ws_size,
                              hipStream_t stream) {
    const float* x = (const float*)d_in[0];
    const int* ei = (const int*)d_in[1];
    const float* eps_e = (const float*)d_in[2];
    const float* eps_n = (const float*)d_in[3];
    int N = in_sizes[0] / 96;
    int E = in_sizes[1] / 2;

    char* p = (char*)d_ws;
    auto alloc = [&](size_t bytes) -> char* {
        char* r = p;
        p += (bytes + 255) & ~(size_t)255;
        return r;
    };
    int* cnt = (int*)alloc((size_t)N * 4);
    float* dinv = (float*)alloc((size_t)N * 4);
    int* offs = (int*)alloc((size_t)(N + 1) * 4);
    int* cursor = (int*)alloc((size_t)N * 4);
    int* bsum = (int*)alloc(256 * 4);
    int* boff = (int*)alloc(256 * 4);
    int2* csr = (int2*)alloc((size_t)E * 8);
    u16* wpack = (u16*)alloc(167936 * 2);
    float* bpack = (float*)alloc(1248 * 4);
    size_t bufBytes = (size_t)N * 192 * 2;
    u16* bufA = (u16*)alloc(bufBytes);
    u16* bufB = (u16*)alloc(bufBytes);
    u16* bufC = (u16*)alloc(bufBytes);
    u16* bufD = (u16*)alloc(bufBytes);
    u16* epsEb = (u16*)alloc((size_t)N * 163 * 2);
    u16* epsNb = (u16*)alloc((size_t)N * 96 * 2);

    hipMemsetAsync(cnt, 0, (size_t)N * 4, stream);
    int gE = (E + 255) / 256, gN = (N + 255) / 256;
    deg_kernel<<<gE, 256, 0, stream>>>(ei, E, cnt);
    dinv_kernel<<<gN, 256, 0, stream>>>(cnt, dinv, N);
    int nb = (N + 1023) / 1024;
    scan1_k<<<nb, 256, 0, stream>>>(cnt, offs, bsum, N);
    scan2_k<<<1, 256, 0, stream>>>(bsum, boff, nb, offs + N);
    scan3_k<<<gN, 256, 0, stream>>>(offs, cursor, boff, N);
    fill_kernel<<<gE, 256, 0, stream>>>(ei, E, dinv, cursor, csr);

    // layers: {w1e,w2e,wme,wle,w4e,w1n,wmn,wln,w5n}
    static const int wi[9] = {4, 6, 8, 10, 12, 14, 16, 18, 20};
    static const int bi[9] = {5, 7, 9, 11, 13, 15, 17, 19, 21};
    static const int Kin[9] = {96, 125, 144, 144, 163, 96, 96, 96, 96};
    static const int Nout[9] = {125, 144, 163, 163, 192, 96, 96, 96, 96};
    static const int KSa[9] = {3, 4, 5, 5, 6, 3, 3, 3, 3};
    static const int NTa[9] = {8, 10, 12, 12, 12, 6, 6, 6, 6};
    static const int wOff[9] = {0, 12288, 32768, 63488, 94208, 131072, 140288, 149504, 158720};
    static const int bOff[9] = {0, 128, 288, 480, 672, 864, 960, 1056, 1152};
    PackArgs pa;
    for (int i = 0; i < 9; i++) {
        pa.W[i] = (const float*)d_in[wi[i]];
        pa.B[i] = (const float*)d_in[bi[i]];
        pa.Kin[i] = Kin[i]; pa.Nout[i] = Nout[i];
        pa.KS[i] = KSa[i];  pa.NT[i] = NTa[i];
        pa.wOff[i] = wOff[i]; pa.bOff[i] = bOff[i];
    }
    pack_weights<<<dim3(32, 9), 256, 0, stream>>>(pa, wpack, bpack);

    const int gp = 2048;             // propagate grid (8192 waves, 32/CU)
    const int gg = (N + 63) / 64;    // gemm grid x

    // xb = bf16(x)                               -> D (96)
    cvt_f2bf_k<<<2048, 256, 0, stream>>>(x, bufD, N * 48);
    // px = P(xb)                                 -> A (96)
    propagate_k<48><<<gp, 256, 0, stream>>>(bufD, bufA, dinv, offs, csr, N);
    // e1 = relu(px W1e+b1e) -> C (128); n1 = relu(px W1n+b1n) -> B (96)
    gemm_dual_relu_k<3, 8, 6><<<dim3(gg, 2), 256, 0, stream>>>(
        bufA, wpack + 0, bpack + 0, bufC, 128, wpack + 131072, bpack + 864, bufB, 96, N);
    // pe1 = P(e1)                                -> A (128)
    propagate_k<64><<<gp, 256, 0, stream>>>(bufC, bufA, dinv, offs, csr, N);
    // e2 = relu(pe1 W2e + b2e)                   -> C (160)
    gemm_k<4, 10, 5, 1, 0><<<dim3(gg, 2), 256, 0, stream>>>(bufA, wpack + 12288, bpack + 128,
                                                            bufC, N, 160);
    // pe2 = P(e2)                                -> A (160)
    propagate_k<80><<<gp, 256, 0, stream>>>(bufC, bufA, dinv, offs, csr, N);
    // eps_e -> bf16 just before use (cache-warm)
    cvt_f2bf_k<<<2048, 256, 0, stream>>>(eps_e, epsEb, N * 163 / 2);
    // lat = (pe2 Wme+bme) + eps_e*exp(pe2 Wle+ble)/10 -> C (192, cols 163.. zero)
    gemm_reparam_k<5, 12, 6, 163><<<dim3(gg, 2), 256, 0, stream>>>(
        bufA, wpack + 32768, bpack + 288, wpack + 63488, bpack + 480, epsEb, bufC, 192, N);
    // plat = P(lat)                              -> D (192)
    propagate_k<96><<<gp, 256, 0, stream>>>(bufC, bufD, dinv, offs, csr, N);
    // edges = sigmoid(plat W4e + b4e)            -> d_out[0 : 192N] (f32)
    gemm_k<6, 12, 6, 2, 1><<<dim3(gg, 2), 256, 0, stream>>>(bufD, wpack + 94208, bpack + 672,
                                                            (float*)d_out, N, 192);
    // pn1 = P(n1)                                -> A (96)
    propagate_k<48><<<gp, 256, 0, stream>>>(bufB, bufA, dinv, offs, csr, N);
    // eps_n -> bf16 just before use
    cvt_f2bf_k<<<2048, 256, 0, stream>>>(eps_n, epsNb, N * 48);
    // nn = (pn1 Wmn+bmn) + eps_n*exp(pn1 Wln+bln)/10 -> C (96)
    gemm_reparam_k<3, 6, 3, 96><<<dim3(gg, 2), 256, 0, stream>>>(
        bufA, wpack + 140288, bpack + 960, wpack + 149504, bpack + 1056, epsNb, bufC, 96, N);
    // pnn = P(nn)                                -> A (96)
    propagate_k<48><<<gp, 256, 0, stream>>>(bufC, bufA, dinv, offs, csr, N);
    // nodes = relu(pnn W5n + b5n)                -> d_out[192N : 288N] (f32)
    gemm_k<3, 6, 3, 1, 1><<<dim3(gg, 2), 256, 0, stream>>>(bufA, wpack + 158720, bpack + 1152,
                                                           (float*)d_out + (size_t)N * 192, N, 96);
}